// Round 7
// baseline (264.106 us; speedup 1.0000x reference)
//
#include <hip/hip_runtime.h>

// Problem constants (from reference): G=256, B=4 -> key space = B*G^3 = 2^26
#define KEYS   (1u << 26)
#define WORDS  (1u << 21)   // KEYS / 32 bitmap words
#define NBLK   2048         // prefix blocks: 2048 blocks * 1024 words = WORDS

__device__ __forceinline__ unsigned key_of(int b, int x, int y, int z) {
  return ((unsigned)b << 24) | ((unsigned)x << 16) | ((unsigned)y << 8) | (unsigned)z;
}

// ---- fast fills (rocclr fillBuffer only hits ~1.6 TB/s; these saturate write BW) ----
__global__ __launch_bounds__(256) void fill_zero_f4(float4* __restrict__ p, size_t n4) {
  size_t i = (size_t)blockIdx.x * 256u + threadIdx.x;
  size_t stride = (size_t)gridDim.x * 256u;
  float4 z = make_float4(0.f, 0.f, 0.f, 0.f);
  for (; i < n4; i += stride) p[i] = z;
}

// ---- bitmap builders ----
__global__ __launch_bounds__(256) void build_bitmaps(const int4* coords, int n,
                                                     unsigned* inbm, unsigned* parbm) {
  int i = blockIdx.x * 256 + threadIdx.x;
  if (i >= n) return;
  int4 c = coords[i];                       // (b,x,y,z)
  unsigned key = key_of(c.x, c.y, c.z, c.w);
  atomicOr(&inbm[key >> 5], 1u << (key & 31));
  unsigned pk = key & 0xFFFEFEFEu;          // floor xyz to even
  atomicOr(&parbm[pk >> 5], 1u << (pk & 31));
}

__global__ __launch_bounds__(256) void build_ref_bitmap(const int4* ref, int n, unsigned* refbm) {
  int i = blockIdx.x * 256 + threadIdx.x;
  if (i >= n) return;
  int4 c = ref[i];
  unsigned key = key_of(c.x, c.y, c.z, c.w);
  atomicOr(&refbm[key >> 5], 1u << (key & 31));
}

// ---- fused: maskbm = parbm & refbm (in place over refbm) + 3 block-sum arrays ----
__global__ __launch_bounds__(256) void popcount3_block_sums(const unsigned* __restrict__ inbm,
                                                            const unsigned* __restrict__ parbm,
                                                            unsigned* __restrict__ refmaskbm,
                                                            unsigned* __restrict__ bsums) {
  __shared__ unsigned s[256];
  unsigned t = threadIdx.x;
  unsigned base = blockIdx.x * 1024u + t * 4u;
  unsigned cin = 0, cpar = 0, cmask = 0;
#pragma unroll
  for (int k = 0; k < 4; k++) {
    unsigned p = parbm[base + k];
    unsigned m = refmaskbm[base + k] & p;
    refmaskbm[base + k] = m;                 // refbm becomes maskbm
    cin += __popc(inbm[base + k]);
    cpar += __popc(p);
    cmask += __popc(m);
  }
  s[t] = cin; __syncthreads();
  for (int off = 128; off > 0; off >>= 1) { if (t < (unsigned)off) s[t] += s[t + off]; __syncthreads(); }
  if (t == 0) bsums[blockIdx.x] = s[0];
  __syncthreads();
  s[t] = cpar; __syncthreads();
  for (int off = 128; off > 0; off >>= 1) { if (t < (unsigned)off) s[t] += s[t + off]; __syncthreads(); }
  if (t == 0) bsums[NBLK + blockIdx.x] = s[0];
  __syncthreads();
  s[t] = cmask; __syncthreads();
  for (int off = 128; off > 0; off >>= 1) { if (t < (unsigned)off) s[t] += s[t + off]; __syncthreads(); }
  if (t == 0) bsums[2 * NBLK + blockIdx.x] = s[0];
}

// ---- scan the 3 block-sum arrays (one block each); mask block writes total M ----
__global__ __launch_bounds__(256) void scan3_block_sums(const unsigned* __restrict__ bsums,
                                                        unsigned* __restrict__ bscan,
                                                        unsigned* __restrict__ counter) {
  __shared__ unsigned s[256];
  unsigned a = blockIdx.x;                   // which array
  const unsigned* src = bsums + a * NBLK;
  unsigned* dst = bscan + a * NBLK;
  unsigned t = threadIdx.x;
  unsigned loc[8], sum = 0;
#pragma unroll
  for (int k = 0; k < 8; k++) { loc[k] = src[t * 8 + k]; sum += loc[k]; }
  s[t] = sum;
  __syncthreads();
  for (int off = 1; off < 256; off <<= 1) {
    unsigned v = (t >= (unsigned)off) ? s[t - off] : 0u;
    __syncthreads();
    s[t] += v;
    __syncthreads();
  }
  if (a == 2 && t == 255) counter[0] = s[255];   // total masked rows M
  unsigned excl = (t == 0) ? 0u : s[t - 1];
#pragma unroll
  for (int k = 0; k < 8; k++) { dst[t * 8 + k] = excl; excl += loc[k]; }
}

// ---- per-word exclusive prefixes for the 3 bitmaps (blockIdx.y selects) ----
__global__ __launch_bounds__(256) void word_prefix3(const unsigned* __restrict__ inbm,
                                                    const unsigned* __restrict__ parbm,
                                                    const unsigned* __restrict__ maskbm,
                                                    const unsigned* __restrict__ bscan,
                                                    unsigned* __restrict__ inpre,
                                                    unsigned* __restrict__ parpre,
                                                    unsigned* __restrict__ maskpre) {
  __shared__ unsigned s[256];
  unsigned a = blockIdx.y;
  const unsigned* bm = (a == 0) ? inbm : (a == 1) ? parbm : maskbm;
  unsigned* pre = (a == 0) ? inpre : (a == 1) ? parpre : maskpre;
  unsigned t = threadIdx.x;
  unsigned base = blockIdx.x * 1024u + t * 4u;
  unsigned c[4], sum = 0;
#pragma unroll
  for (int k = 0; k < 4; k++) { c[k] = __popc(bm[base + k]); sum += c[k]; }
  s[t] = sum;
  __syncthreads();
  for (int off = 1; off < 256; off <<= 1) {
    unsigned v = (t >= (unsigned)off) ? s[t - off] : 0u;
    __syncthreads();
    s[t] += v;
    __syncthreads();
  }
  unsigned excl = ((t == 0) ? 0u : s[t - 1]) + bscan[a * NBLK + blockIdx.x];
#pragma unroll
  for (int k = 0; k < 4; k++) { pre[base + k] = excl; excl += c[k]; }
}

// ---- scatter input row indices into sorted-key order ----
__global__ __launch_bounds__(256) void build_sorted_row(const int4* coords, int n,
                                                        const unsigned* inbm, const unsigned* inpre,
                                                        unsigned* srow) {
  int i = blockIdx.x * 256 + threadIdx.x;
  if (i >= n) return;
  int4 c = coords[i];
  unsigned key = key_of(c.x, c.y, c.z, c.w);
  unsigned w = key >> 5, b = key & 31;
  unsigned r = inpre[w] + __popc(inbm[w] & ((1u << b) - 1u));
  srow[r] = (unsigned)i;
}

// ---- default out_coords = -1 ----
__global__ __launch_bounds__(256) void fill_coords_default(float4* oc, int n) {
  int i = blockIdx.x * 256 + threadIdx.x;
  if (i < n) oc[i] = make_float4(-1.f, -1.f, -1.f, -1.f);
}

// ---- emit out_coords / mask / compact masked list — NO atomics ----
__global__ __launch_bounds__(256) void emit_outputs(const unsigned* __restrict__ parbm,
                                                    const unsigned* __restrict__ parpre,
                                                    const unsigned* __restrict__ maskbm,
                                                    const unsigned* __restrict__ maskpre,
                                                    float4* __restrict__ out_coords,
                                                    float* __restrict__ out_mask,
                                                    uint2* __restrict__ mlist) {
  unsigned w = blockIdx.x * 256u + threadIdx.x;
  unsigned bits = parbm[w];
  if (!bits) return;
  unsigned mb = maskbm[w];
  unsigned r = parpre[w];
  unsigned j = maskpre[w];
  while (bits) {
    unsigned b = (unsigned)__ffs(bits) - 1u;
    bits &= bits - 1u;
    unsigned key = (w << 5) | b;
    out_coords[r] = make_float4((float)(key >> 24), (float)((key >> 16) & 255u),
                                (float)((key >> 8) & 255u), (float)(key & 255u));
    if ((mb >> b) & 1u) {
      out_mask[r] = 1.0f;
      mlist[j++] = make_uint2(key, r);
    }
    r++;
  }
}

// ---- phase A: resolve 8 children per masked row (one thread per (row,child)) ----
__global__ __launch_bounds__(256) void resolve_children(const unsigned* __restrict__ inbm,
                                                        const unsigned* __restrict__ inpre,
                                                        const unsigned* __restrict__ srow,
                                                        const uint2* __restrict__ mlist,
                                                        const unsigned* __restrict__ counter,
                                                        unsigned* __restrict__ cidx) {
  unsigned tid = blockIdx.x * 256u + threadIdx.x;
  unsigned j = tid >> 3, i = tid & 7u;
  if (j >= counter[0]) return;
  unsigned key = mlist[j].x;
  unsigned ck = key + ((i >> 2) << 16) + (((i >> 1) & 1u) << 8) + (i & 1u);
  unsigned word = inbm[ck >> 5];
  unsigned bit = ck & 31u;
  unsigned v = 0u;
  if ((word >> bit) & 1u) {
    unsigned rk = inpre[ck >> 5] + __popc(word & ((1u << bit) - 1u));
    v = srow[rk] + 1u;                       // row index + 1 (0 = absent)
  }
  cidx[tid] = v;
}

// ---- phase B: conv with W staged in LDS; one wave per masked row ----
// 1024 threads (16 waves), 64 KB LDS -> 2 blocks/CU = 32 waves/CU (full occupancy).
// __launch_bounds__ 2nd arg = min waves per EU: 2 blocks * 16 waves / 4 EU = 8.
// LDS read lw[i*2048 + k*64 + lane]: 64 consecutive lanes -> 2 lanes/bank (free).
__global__ __launch_bounds__(1024, 8) void conv_lds(const float* __restrict__ feats,
                                                    const float* __restrict__ Wg,
                                                    const float* __restrict__ bias,
                                                    const unsigned* __restrict__ cidx,
                                                    const uint2* __restrict__ mlist,
                                                    const unsigned* __restrict__ counter,
                                                    float* __restrict__ out_feats) {
  __shared__ float lw[16384];                // all of W: 8*32*64 floats = 64 KB
  for (unsigned t = threadIdx.x; t < 4096u; t += 1024u)
    ((float4*)lw)[t] = ((const float4*)Wg)[t];
  __syncthreads();

  unsigned lane = threadIdx.x & 63u;
  unsigned wave = blockIdx.x * 16u + (threadIdx.x >> 6);
  unsigned nwaves = gridDim.x * 16u;
  unsigned M = counter[0];
  float bv = bias[lane];
  for (unsigned j = wave; j < M; j += nwaves) {
    unsigned r = mlist[j].y;
    uint4 c0 = *(const uint4*)(cidx + (size_t)j * 8u);
    uint4 c1 = *(const uint4*)(cidx + (size_t)j * 8u + 4u);
    unsigned cs[8] = {c0.x, c0.y, c0.z, c0.w, c1.x, c1.y, c1.z, c1.w};
    float acc = bv;
#pragma unroll
    for (int i = 0; i < 8; i++) {
      unsigned v = (unsigned)__builtin_amdgcn_readfirstlane((int)cs[i]);
      if (v) {                               // wave-uniform branch
        const float* f = feats + (size_t)(v - 1u) * 32u;   // SGPR base -> s_load
        const float* wl = lw + i * 2048 + lane;
#pragma unroll
        for (int k = 0; k < 32; k++) acc = fmaf(f[k], wl[k * 64], acc);
      }
    }
    out_feats[(size_t)r * 64u + lane] = acc;
  }
}

extern "C" void kernel_launch(void* const* d_in, const int* in_sizes, int n_in,
                              void* d_out, int out_size, void* d_ws, size_t ws_size,
                              hipStream_t stream) {
  const float* feats = (const float*)d_in[0];
  const float* W     = (const float*)d_in[1];
  const float* bias  = (const float*)d_in[2];
  const int4*  coords = (const int4*)d_in[3];
  const int4*  ref    = (const int4*)d_in[4];
  int N    = in_sizes[0] / 32;
  int NREF = in_sizes[4] / 4;

  float* out_coords = (float*)d_out;
  float* out_feats  = out_coords + (size_t)N * 4;
  float* out_mask   = out_feats + (size_t)N * 64;

  char* ws = (char*)d_ws;
  unsigned* inbm    = (unsigned*)(ws);                  // 8 MB
  unsigned* parbm   = (unsigned*)(ws + (8u << 20));     // 8 MB
  unsigned* refbm   = (unsigned*)(ws + (16u << 20));    // 8 MB (becomes maskbm)
  unsigned* maskbm  = refbm;
  unsigned* inpre   = (unsigned*)(ws + (24u << 20));    // 8 MB
  unsigned* parpre  = (unsigned*)(ws + (32u << 20));    // 8 MB
  unsigned* maskpre = (unsigned*)(ws + (40u << 20));    // 8 MB
  unsigned* srow    = (unsigned*)(ws + (48u << 20));    // 4 MB (N u32)
  uint2*    mlist   = (uint2*)   (ws + (52u << 20));    // 3.2 MB (<= NREF entries)
  unsigned* bsums   = (unsigned*)(ws + (56u << 20));            // 3*2048 u32
  unsigned* bscan   = (unsigned*)(ws + (56u << 20) + 32768);    // 3*2048 u32
  unsigned* counter = (unsigned*)(ws + (56u << 20) + 65536);    // 1 u32
  unsigned* cidx    = (unsigned*)(ws + (57u << 20));    // NREF*8 u32 (12.8 MB)

  // fast zero fills: bitmaps (24 MB) and feats+mask out region (260 MB)
  fill_zero_f4<<<512, 256, 0, stream>>>((float4*)inbm, (size_t)(24u << 20) / 16u);
  fill_zero_f4<<<4096, 256, 0, stream>>>((float4*)out_feats,
                                         (size_t)N * 65u * 4u / 16u);

  int nb = (N + 255) / 256;
  build_bitmaps<<<nb, 256, 0, stream>>>(coords, N, inbm, parbm);
  build_ref_bitmap<<<(NREF + 255) / 256, 256, 0, stream>>>(ref, NREF, refbm);

  popcount3_block_sums<<<NBLK, 256, 0, stream>>>(inbm, parbm, refbm, bsums);
  scan3_block_sums<<<3, 256, 0, stream>>>(bsums, bscan, counter);
  word_prefix3<<<dim3(NBLK, 3), 256, 0, stream>>>(inbm, parbm, maskbm, bscan,
                                                  inpre, parpre, maskpre);

  build_sorted_row<<<nb, 256, 0, stream>>>(coords, N, inbm, inpre, srow);
  fill_coords_default<<<nb, 256, 0, stream>>>((float4*)out_coords, N);
  emit_outputs<<<WORDS / 256, 256, 0, stream>>>(parbm, parpre, maskbm, maskpre,
                                                (float4*)out_coords, out_mask, mlist);

  int nres = ((NREF * 8) + 255) / 256;
  resolve_children<<<nres, 256, 0, stream>>>(inbm, inpre, srow, mlist, counter, cidx);
  conv_lds<<<512, 1024, 0, stream>>>(feats, W, bias, cidx, mlist, counter, out_feats);
}

// Round 8
// 246.218 us; speedup vs baseline: 1.0727x; 1.0727x over previous
//
#include <hip/hip_runtime.h>

// Problem constants (from reference): G=256, B=4 -> key space = B*G^3 = 2^26
#define KEYS   (1u << 26)
#define WORDS  (1u << 21)   // KEYS / 32 bitmap words
#define NBLK   2048         // prefix blocks: 2048 blocks * 1024 words = WORDS

__device__ __forceinline__ unsigned key_of(int b, int x, int y, int z) {
  return ((unsigned)b << 24) | ((unsigned)x << 16) | ((unsigned)y << 8) | (unsigned)z;
}

// ---- one fused fill: bitmaps=0 (24MB), out_feats+mask=0 (260MB), out_coords=-1 (16MB) ----
__global__ __launch_bounds__(256) void fill_all(float4* __restrict__ bm,   size_t n4_bm,
                                                float4* __restrict__ ofm,  size_t n4_ofm,
                                                float4* __restrict__ oc,   size_t n4_oc) {
  size_t stride = (size_t)gridDim.x * 256u;
  size_t i0 = (size_t)blockIdx.x * 256u + threadIdx.x;
  float4 z = make_float4(0.f, 0.f, 0.f, 0.f);
  float4 m1 = make_float4(-1.f, -1.f, -1.f, -1.f);
  for (size_t i = i0; i < n4_bm; i += stride) bm[i] = z;
  for (size_t i = i0; i < n4_ofm; i += stride) ofm[i] = z;
  for (size_t i = i0; i < n4_oc; i += stride) oc[i] = m1;
}

// ---- all three bitmap builds in one dispatch (block-range partition) ----
__global__ __launch_bounds__(256) void build_all(const int4* __restrict__ coords, int n,
                                                 const int4* __restrict__ ref, int nref,
                                                 unsigned* __restrict__ inbm,
                                                 unsigned* __restrict__ parbm,
                                                 unsigned* __restrict__ refbm, int nbN) {
  if ((int)blockIdx.x < nbN) {
    int i = blockIdx.x * 256 + threadIdx.x;
    if (i >= n) return;
    int4 c = coords[i];                     // (b,x,y,z)
    unsigned key = key_of(c.x, c.y, c.z, c.w);
    atomicOr(&inbm[key >> 5], 1u << (key & 31));
    unsigned pk = key & 0xFFFEFEFEu;        // floor xyz to even
    atomicOr(&parbm[pk >> 5], 1u << (pk & 31));
  } else {
    int i = (blockIdx.x - nbN) * 256 + threadIdx.x;
    if (i >= nref) return;
    int4 c = ref[i];
    unsigned key = key_of(c.x, c.y, c.z, c.w);
    atomicOr(&refbm[key >> 5], 1u << (key & 31));
  }
}

// ---- fused: maskbm = parbm & refbm (in place over refbm) + 3 block-sum arrays ----
__global__ __launch_bounds__(256) void popcount3_block_sums(const unsigned* __restrict__ inbm,
                                                            const unsigned* __restrict__ parbm,
                                                            unsigned* __restrict__ refmaskbm,
                                                            unsigned* __restrict__ bsums) {
  __shared__ unsigned s[256];
  unsigned t = threadIdx.x;
  unsigned base = blockIdx.x * 1024u + t * 4u;
  unsigned cin = 0, cpar = 0, cmask = 0;
#pragma unroll
  for (int k = 0; k < 4; k++) {
    unsigned p = parbm[base + k];
    unsigned m = refmaskbm[base + k] & p;
    refmaskbm[base + k] = m;                 // refbm becomes maskbm
    cin += __popc(inbm[base + k]);
    cpar += __popc(p);
    cmask += __popc(m);
  }
  s[t] = cin; __syncthreads();
  for (int off = 128; off > 0; off >>= 1) { if (t < (unsigned)off) s[t] += s[t + off]; __syncthreads(); }
  if (t == 0) bsums[blockIdx.x] = s[0];
  __syncthreads();
  s[t] = cpar; __syncthreads();
  for (int off = 128; off > 0; off >>= 1) { if (t < (unsigned)off) s[t] += s[t + off]; __syncthreads(); }
  if (t == 0) bsums[NBLK + blockIdx.x] = s[0];
  __syncthreads();
  s[t] = cmask; __syncthreads();
  for (int off = 128; off > 0; off >>= 1) { if (t < (unsigned)off) s[t] += s[t + off]; __syncthreads(); }
  if (t == 0) bsums[2 * NBLK + blockIdx.x] = s[0];
}

// ---- scan the 3 block-sum arrays (one block each); mask block writes total M ----
__global__ __launch_bounds__(256) void scan3_block_sums(const unsigned* __restrict__ bsums,
                                                        unsigned* __restrict__ bscan,
                                                        unsigned* __restrict__ counter) {
  __shared__ unsigned s[256];
  unsigned a = blockIdx.x;                   // which array
  const unsigned* src = bsums + a * NBLK;
  unsigned* dst = bscan + a * NBLK;
  unsigned t = threadIdx.x;
  unsigned loc[8], sum = 0;
#pragma unroll
  for (int k = 0; k < 8; k++) { loc[k] = src[t * 8 + k]; sum += loc[k]; }
  s[t] = sum;
  __syncthreads();
  for (int off = 1; off < 256; off <<= 1) {
    unsigned v = (t >= (unsigned)off) ? s[t - off] : 0u;
    __syncthreads();
    s[t] += v;
    __syncthreads();
  }
  if (a == 2 && t == 255) counter[0] = s[255];   // total masked rows M
  unsigned excl = (t == 0) ? 0u : s[t - 1];
#pragma unroll
  for (int k = 0; k < 8; k++) { dst[t * 8 + k] = excl; excl += loc[k]; }
}

// ---- per-word exclusive prefixes for the 3 bitmaps (blockIdx.y selects) ----
__global__ __launch_bounds__(256) void word_prefix3(const unsigned* __restrict__ inbm,
                                                    const unsigned* __restrict__ parbm,
                                                    const unsigned* __restrict__ maskbm,
                                                    const unsigned* __restrict__ bscan,
                                                    unsigned* __restrict__ inpre,
                                                    unsigned* __restrict__ parpre,
                                                    unsigned* __restrict__ maskpre) {
  __shared__ unsigned s[256];
  unsigned a = blockIdx.y;
  const unsigned* bm = (a == 0) ? inbm : (a == 1) ? parbm : maskbm;
  unsigned* pre = (a == 0) ? inpre : (a == 1) ? parpre : maskpre;
  unsigned t = threadIdx.x;
  unsigned base = blockIdx.x * 1024u + t * 4u;
  unsigned c[4], sum = 0;
#pragma unroll
  for (int k = 0; k < 4; k++) { c[k] = __popc(bm[base + k]); sum += c[k]; }
  s[t] = sum;
  __syncthreads();
  for (int off = 1; off < 256; off <<= 1) {
    unsigned v = (t >= (unsigned)off) ? s[t - off] : 0u;
    __syncthreads();
    s[t] += v;
    __syncthreads();
  }
  unsigned excl = ((t == 0) ? 0u : s[t - 1]) + bscan[a * NBLK + blockIdx.x];
#pragma unroll
  for (int k = 0; k < 4; k++) { pre[base + k] = excl; excl += c[k]; }
}

// ---- fused: build_sorted_row (blocks [0,nbN)) + emit_outputs (blocks [nbN, nbN+8192)) ----
__global__ __launch_bounds__(256) void emit_sorted(const int4* __restrict__ coords, int n,
                                                   const unsigned* __restrict__ inbm,
                                                   const unsigned* __restrict__ inpre,
                                                   unsigned* __restrict__ srow,
                                                   const unsigned* __restrict__ parbm,
                                                   const unsigned* __restrict__ parpre,
                                                   const unsigned* __restrict__ maskbm,
                                                   const unsigned* __restrict__ maskpre,
                                                   float4* __restrict__ out_coords,
                                                   float* __restrict__ out_mask,
                                                   uint2* __restrict__ mlist, int nbN) {
  if ((int)blockIdx.x < nbN) {
    int i = blockIdx.x * 256 + threadIdx.x;
    if (i >= n) return;
    int4 c = coords[i];
    unsigned key = key_of(c.x, c.y, c.z, c.w);
    unsigned w = key >> 5, b = key & 31;
    unsigned r = inpre[w] + __popc(inbm[w] & ((1u << b) - 1u));
    srow[r] = (unsigned)i;
    return;
  }
  unsigned w = (blockIdx.x - nbN) * 256u + threadIdx.x;
  unsigned bits = parbm[w];
  if (!bits) return;
  unsigned mb = maskbm[w];
  unsigned r = parpre[w];
  unsigned j = maskpre[w];
  while (bits) {
    unsigned b = (unsigned)__ffs(bits) - 1u;
    bits &= bits - 1u;
    unsigned key = (w << 5) | b;
    out_coords[r] = make_float4((float)(key >> 24), (float)((key >> 16) & 255u),
                                (float)((key >> 8) & 255u), (float)(key & 255u));
    if ((mb >> b) & 1u) {
      out_mask[r] = 1.0f;
      mlist[j++] = make_uint2(key, r);
    }
    r++;
  }
}

// ---- conv with W in LDS; probes fused in-wave (lanes 0-7 probe the 8 children) ----
// 1024 threads (16 waves), 64 KB LDS -> 2 blocks/CU = 32 waves/CU.
// __launch_bounds__ 2nd arg = min waves per EU: 2 blocks * 16 waves / 4 EU = 8.
__global__ __launch_bounds__(1024, 8) void conv_lds(const float* __restrict__ feats,
                                                    const float* __restrict__ Wg,
                                                    const float* __restrict__ bias,
                                                    const unsigned* __restrict__ inbm,
                                                    const unsigned* __restrict__ inpre,
                                                    const unsigned* __restrict__ srow,
                                                    const uint2* __restrict__ mlist,
                                                    const unsigned* __restrict__ counter,
                                                    float* __restrict__ out_feats) {
  __shared__ float lw[16384];                // all of W: 8*32*64 floats = 64 KB
  for (unsigned t = threadIdx.x; t < 4096u; t += 1024u)
    ((float4*)lw)[t] = ((const float4*)Wg)[t];
  __syncthreads();

  unsigned lane = threadIdx.x & 63u;
  unsigned wave = blockIdx.x * 16u + (threadIdx.x >> 6);
  unsigned nwaves = gridDim.x * 16u;
  unsigned M = counter[0];
  float bv = bias[lane];
  for (unsigned j = wave; j < M; j += nwaves) {
    uint2 e = mlist[j];                      // same addr all lanes -> broadcast
    unsigned key = e.x, r = e.y;
    // lanes 0-7 probe children in parallel (breaks R2's serial probe chain)
    unsigned v = 0u;
    if (lane < 8u) {
      unsigned ck = key + ((lane >> 2) << 16) + (((lane >> 1) & 1u) << 8) + (lane & 1u);
      unsigned word = inbm[ck >> 5];
      unsigned bit = ck & 31u;
      if ((word >> bit) & 1u) {
        unsigned rk = inpre[ck >> 5] + __popc(word & ((1u << bit) - 1u));
        v = srow[rk] + 1u;                   // row + 1 (0 = absent)
      }
    }
    float acc = bv;
#pragma unroll
    for (int i = 0; i < 8; i++) {
      unsigned vi = (unsigned)__builtin_amdgcn_readfirstlane(__shfl((int)v, i, 64));
      if (vi) {                              // wave-uniform branch
        const float* f = feats + (size_t)(vi - 1u) * 32u;   // SGPR base -> s_load
        const float* wl = lw + i * 2048 + lane;
#pragma unroll
        for (int k = 0; k < 32; k++) acc = fmaf(f[k], wl[k * 64], acc);
      }
    }
    out_feats[(size_t)r * 64u + lane] = acc;
  }
}

extern "C" void kernel_launch(void* const* d_in, const int* in_sizes, int n_in,
                              void* d_out, int out_size, void* d_ws, size_t ws_size,
                              hipStream_t stream) {
  const float* feats = (const float*)d_in[0];
  const float* W     = (const float*)d_in[1];
  const float* bias  = (const float*)d_in[2];
  const int4*  coords = (const int4*)d_in[3];
  const int4*  ref    = (const int4*)d_in[4];
  int N    = in_sizes[0] / 32;
  int NREF = in_sizes[4] / 4;

  float* out_coords = (float*)d_out;
  float* out_feats  = out_coords + (size_t)N * 4;
  float* out_mask   = out_feats + (size_t)N * 64;

  char* ws = (char*)d_ws;
  unsigned* inbm    = (unsigned*)(ws);                  // 8 MB
  unsigned* parbm   = (unsigned*)(ws + (8u << 20));     // 8 MB
  unsigned* refbm   = (unsigned*)(ws + (16u << 20));    // 8 MB (becomes maskbm)
  unsigned* maskbm  = refbm;
  unsigned* inpre   = (unsigned*)(ws + (24u << 20));    // 8 MB
  unsigned* parpre  = (unsigned*)(ws + (32u << 20));    // 8 MB
  unsigned* maskpre = (unsigned*)(ws + (40u << 20));    // 8 MB
  unsigned* srow    = (unsigned*)(ws + (48u << 20));    // 4 MB (N u32)
  uint2*    mlist   = (uint2*)   (ws + (52u << 20));    // 3.2 MB (<= NREF entries)
  unsigned* bsums   = (unsigned*)(ws + (56u << 20));            // 3*2048 u32
  unsigned* bscan   = (unsigned*)(ws + (56u << 20) + 32768);    // 3*2048 u32
  unsigned* counter = (unsigned*)(ws + (56u << 20) + 65536);    // 1 u32

  int nbN = (N + 255) / 256;
  int nbR = (NREF + 255) / 256;

  // 1) fused fill: bitmaps 24MB=0, feats+mask 260MB=0, coords 16MB=-1
  fill_all<<<4096, 256, 0, stream>>>((float4*)inbm, (size_t)(24u << 20) / 16u,
                                     (float4*)out_feats, (size_t)N * 65u * 4u / 16u,
                                     (float4*)out_coords, (size_t)N);
  // 2) all bitmap builds
  build_all<<<nbN + nbR, 256, 0, stream>>>(coords, N, ref, NREF, inbm, parbm, refbm, nbN);
  // 3-5) rank structures
  popcount3_block_sums<<<NBLK, 256, 0, stream>>>(inbm, parbm, refbm, bsums);
  scan3_block_sums<<<3, 256, 0, stream>>>(bsums, bscan, counter);
  word_prefix3<<<dim3(NBLK, 3), 256, 0, stream>>>(inbm, parbm, maskbm, bscan,
                                                  inpre, parpre, maskpre);
  // 6) sorted-row scatter + output emit
  emit_sorted<<<nbN + WORDS / 256, 256, 0, stream>>>(coords, N, inbm, inpre, srow,
                                                     parbm, parpre, maskbm, maskpre,
                                                     (float4*)out_coords, out_mask,
                                                     mlist, nbN);
  // 7) conv with in-wave probing
  conv_lds<<<512, 1024, 0, stream>>>(feats, W, bias, inbm, inpre, srow, mlist, counter,
                                     out_feats);
}